// Round 4
// baseline (124.235 us; speedup 1.0000x reference)
//
#include <hip/hip_runtime.h>
#include <math.h>

#define B_   4
#define K_   200
#define DIM_ 256
#define T_   800

#define S_UP 68   // padded row stride for the A-partial transpose pool
#define CW_R 20   // padded const row: [beta0, beta1, B0..B15, pad, pad] (80 B)

__device__ __forceinline__ float silu_f(float x) {
    // x * rcp(1+e^-x): v_exp + v_add + v_rcp + v_mul (vs ~9-op IEEE divide seq)
    return x * __builtin_amdgcn_rcpf(1.0f + __expf(-x));
}

// ---------------------------------------------------------------------------
// Prep: conv (wave=token, lane=4-ch slice, coalesced) + scan + const folding.
// Writes cw[b][k][0..17]: 0 beta0, 1 beta1, 2..17 B_j  (token-major, 20-pad).
// Also writes w2T (sw1_w2 transposed) at cw + B*K*20 for scalar-load access
// in main. Grid (50, B_), 256 threads.
// ---------------------------------------------------------------------------
__global__ __launch_bounds__(256) void prep_kernel(
        const float* __restrict__ dur,
        const float* __restrict__ feats,
        const float* __restrict__ c1w, const float* __restrict__ c1b,
        const float* __restrict__ c2w, const float* __restrict__ c2b,
        const float* __restrict__ sw1_w1, const float* __restrict__ sw1_b1,
        const float* __restrict__ sw1_w2,
        const float* __restrict__ sw2_w1, const float* __restrict__ sw2_b1,
        float* __restrict__ cw) {
    const int b = blockIdx.y, k0 = blockIdx.x * 4;
    const int tid = threadIdx.x, w = tid >> 6, l = tid & 63;

    __shared__ float wT[16][772];        // wT[oc][tap*256+c]  (oc>=8 -> conv2)
    __shared__ float red[64][S_UP];      // cross-lane reduce scratch
    __shared__ float sSc[K_], sEc[K_];
    __shared__ float sfeat[4][16];       // conv outputs (post-silu)

    // block (0,0): transpose sw1_w2 into workspace tail (w2T[j][p] = w2[p][j])
    if (blockIdx.x == 0 && blockIdx.y == 0) {
        cw[(size_t)B_ * K_ * CW_R + tid] = sw1_w2[((tid & 15) * 16) + (tid >> 4)];
    }

    // stage transposed conv weights (reads coalesced)
    for (int i = tid; i < 3 * DIM_ * 8; i += 256) {
        int tc = i >> 3, o = i & 7;
        wT[o][tc]     = c1w[i];
        wT[8 + o][tc] = c2w[i];
    }
    // wave 0: inclusive scan of 200 durations
    if (tid < 64) {
        float4 dv = make_float4(0.f, 0.f, 0.f, 0.f);
        if (tid < 50) dv = *(const float4*)&dur[b * K_ + tid * 4];
        float s0 = dv.x, s1 = s0 + dv.y, s2 = s1 + dv.z, s3 = s2 + dv.w;
        float sc = s3;
#pragma unroll
        for (int off = 1; off < 64; off <<= 1) {
            float v = __shfl_up(sc, off);
            if (tid >= off) sc += v;
        }
        float excl = sc - s3;
        if (tid < 50) {
            *(float4*)&sSc[tid * 4] = make_float4(excl, excl + s0, excl + s1, excl + s2);
            *(float4*)&sEc[tid * 4] = make_float4(excl + s0, excl + s1, excl + s2, excl + s3);
        }
    }
    __syncthreads();

    // conv: wave w owns token k0+w; lane l owns channels 4l..4l+3
    {
        const int k = k0 + w;
        const float4* f4 = (const float4*)feats;
        float4 fv[3];
#pragma unroll
        for (int tap = 0; tap < 3; ++tap) {
            int kk = k - 1 + tap;
            bool valid = (kk >= 0 && kk < K_);
            int kc = valid ? kk : 0;
            float4 v = f4[(size_t)(b * K_ + kc) * 64 + l];
            fv[tap] = valid ? v : make_float4(0.f, 0.f, 0.f, 0.f);
        }
        float acc[16];
#pragma unroll
        for (int oc = 0; oc < 16; ++oc) acc[oc] = 0.f;
#pragma unroll
        for (int tap = 0; tap < 3; ++tap) {
#pragma unroll
            for (int oc = 0; oc < 16; ++oc) {
                float4 wv = *(const float4*)&wT[oc][tap * DIM_ + 4 * l];
                acc[oc] += fv[tap].x * wv.x + fv[tap].y * wv.y
                         + fv[tap].z * wv.z + fv[tap].w * wv.w;
            }
        }
#pragma unroll
        for (int oc = 0; oc < 16; ++oc) red[w * 16 + oc][l] = acc[oc];
    }
    __syncthreads();
    // reduce 64 lanes -> sfeat
    {
        const int rwv = tid >> 6, oc = (tid >> 2) & 15, rq = tid & 3;
        const float* base = &red[rwv * 16 + oc][rq * 16];
        float4 b0 = *(const float4*)&base[0];
        float4 b1 = *(const float4*)&base[4];
        float4 b2 = *(const float4*)&base[8];
        float4 b3 = *(const float4*)&base[12];
        float s = b0.x + b0.y + b0.z + b0.w + b1.x + b1.y + b1.z + b1.w
                + b2.x + b2.y + b2.z + b2.w + b3.x + b3.y + b3.z + b3.w;
        s += __shfl_down(s, 1);
        s += __shfl_down(s, 2);
        if (rq == 0) {
            float bias = (oc < 8) ? c1b[oc] : c2b[oc & 7];
            sfeat[rwv][oc] = silu_f(s + bias);
        }
    }
    __syncthreads();

    // consts for this block's 4 tokens (token-major rows)
    if (tid < 64) {                       // B_j: j = tid>>2, token = tid&3
        const int j = tid >> 2, klc = tid & 3, kk = k0 + klc;
        float st = sSc[kk], en = sEc[kk];
        float a = sw1_b1[j] - st * sw1_w1[j] + en * sw1_w1[16 + j];
#pragma unroll
        for (int i = 0; i < 8; ++i) a += sfeat[klc][i] * sw1_w1[(2 + i) * 16 + j];
        cw[(size_t)(b * K_ + kk) * CW_R + 2 + j] = a;
    } else if (tid < 72) {                // betas
        const int idx = tid - 64, which = idx >> 2, klc = idx & 3, kk = k0 + klc;
        float st = sSc[kk], en = sEc[kk];
        float a = sw2_b1[which] - st * sw2_w1[which] + en * sw2_w1[2 + which];
#pragma unroll
        for (int i = 0; i < 8; ++i) a += sfeat[klc][8 + i] * sw2_w1[(2 + i) * 2 + which];
        cw[(size_t)(b * K_ + kk) * CW_R + which] = a;
    }
}

// ---------------------------------------------------------------------------
// Main: 4 frames/block (wave w <-> frame t0+w), grid (T/4, B), 256 thr.
// launch_bounds(256,4): <=128 VGPR -> 4 blocks/CU -> all 800 blocks
// co-resident (LDS 37.2KB*4=149KB <= 160KB). Register pressure held down by
// per-chunk const-row reload (phase-2 loop interchange) + pf depth 4.
// ---------------------------------------------------------------------------
__global__ __launch_bounds__(256, 4) void main_kernel(
        const float* __restrict__ feats,
        const float* __restrict__ cw,
        const float* __restrict__ sw1_w1, const float* __restrict__ sw1_b2,
        const float* __restrict__ sw2_w1, const float* __restrict__ sw2_w2,
        const float* __restrict__ sw2_b2,
        const float* __restrict__ p1_w,   const float* __restrict__ p1_b,
        const float* __restrict__ p2_w,   const float* __restrict__ p2_b,
        float* __restrict__ out) {
    const int t0 = blockIdx.x * 4, b = blockIdx.y;
    const int tid = threadIdx.x, w = tid >> 6, l = tid & 63;
    const int t = t0 + w;

    __shared__ alignas(16) float apool[64 * S_UP];   // A-partials (transpose pool)
    __shared__ alignas(16) float opool[16 * 256];    // O-partials [(w*4+f)][256]
    __shared__ alignas(16) float W4[K_][4];
    __shared__ alignas(16) float At[16][4];

    const float* __restrict__ w2T = cw + (size_t)B_ * K_ * CW_R;  // [j][p], uniform

    const float* cbg = cw + (size_t)b * K_ * CW_R;
    int kc[4];
#pragma unroll
    for (int i = 0; i < 4; ++i) { int k = l + 64 * i; kc[i] = (k < K_) ? k : (K_ - 1); }

    // ---- row heads only for phase 1 (beta0, beta1 in .x/.y) ----
    float c0[4], c1[4];
#pragma unroll
    for (int i = 0; i < 4; ++i) {
        float4 h = *(const float4*)(cbg + (size_t)kc[i] * CW_R);
        c0[i] = h.x; c1[i] = h.y;
    }

    const float tf = (float)t;
    const float a0 = sw2_w1[0] - sw2_w1[2], a1 = sw2_w1[1] - sw2_w1[3];
    const float rw20 = sw2_w2[0], rw21 = sw2_w2[1], rw22 = sw2_w2[2], rw23 = sw2_w2[3];
    const float rb20 = sw2_b2[0], rb21 = sw2_b2[1];
    const float p10 = p1_w[0], p11 = p1_w[1], p1b0 = p1_b[0];

    // ---- phase 1: logits + wave softmax ----
    float lg[4];
#pragma unroll
    for (int i = 0; i < 4; ++i) {
        float h0 = silu_f(fmaf(a0, tf, c0[i]));
        float h1 = silu_f(fmaf(a1, tf, c1[i]));
        float g0 = silu_f(rb20 + h0 * rw20 + h1 * rw22);
        float g1 = silu_f(rb21 + h0 * rw21 + h1 * rw23);
        lg[i] = (l + 64 * i < K_) ? (g0 * p10 + g1 * p11 + p1b0) : -1e30f;
    }
    float m = fmaxf(fmaxf(lg[0], lg[1]), fmaxf(lg[2], lg[3]));
#pragma unroll
    for (int off = 32; off > 0; off >>= 1) m = fmaxf(m, __shfl_xor(m, off));
    float e0 = __expf(lg[0] - m), e1 = __expf(lg[1] - m);
    float e2 = __expf(lg[2] - m), e3 = __expf(lg[3] - m);
    float ssum = e0 + e1 + e2 + e3;
#pragma unroll
    for (int off = 32; off > 0; off >>= 1) ssum += __shfl_xor(ssum, off);
    float inv = __builtin_amdgcn_rcpf(ssum);
    float wgt[4] = { e0 * inv, e1 * inv, e2 * inv, e3 * inv };
#pragma unroll
    for (int i = 0; i < 4; ++i) { int k = l + 64 * i; if (k < K_) W4[k][w] = wgt[i]; }

    // ---- prefetch first 4 phase-3 feats tiles ----
    const int kb = w * 50;
    const float4* fB4 = (const float4*)(feats + (size_t)b * K_ * DIM_);
    float4 pf[4];
#pragma unroll
    for (int q = 0; q < 4; ++q) pf[q] = fB4[(size_t)(kb + q) * 64 + l];

    // ---- phase 2 (loop-interchanged, low register pressure):
    //      per chunk i: reload const row, hv = silu(ajt+B), acc[j] += wgt*silu(hv@w2)
    float ajt[16];
#pragma unroll
    for (int j = 0; j < 16; ++j) ajt[j] = (sw1_w1[j] - sw1_w1[16 + j]) * tf;
    float acc[16];
#pragma unroll
    for (int j = 0; j < 16; ++j) acc[j] = 0.f;
#pragma unroll
    for (int i = 0; i < 4; ++i) {
        const float* base = cbg + (size_t)kc[i] * CW_R;
        float r[20];
#pragma unroll
        for (int q = 0; q < 5; ++q) *(float4*)&r[4 * q] = *(const float4*)(base + 4 * q);
        float hv[16];
#pragma unroll
        for (int j = 0; j < 16; ++j) hv[j] = silu_f(ajt[j] + r[2 + j]);
        const float wi = wgt[i];
#pragma unroll
        for (int j = 0; j < 16; ++j) {
            const float* __restrict__ wj = w2T + j * 16;   // uniform -> s_load
            float c = sw1_b2[j];
#pragma unroll
            for (int p = 0; p < 16; ++p) c += hv[p] * wj[p];
            acc[j] = fmaf(wi, silu_f(c), acc[j]);
        }
    }
#pragma unroll
    for (int j = 0; j < 16; ++j) apool[(w * 16 + j) * S_UP + l] = acc[j];

    __syncthreads();   // barrier 1: A-partials + W4 visible

    // ---- A transpose-reduce (reads apool; phase 3 writes opool — disjoint) ----
    {
        const int rwv = tid >> 6, rj = (tid >> 2) & 15, rq = tid & 3;
        const float* base = &apool[(rwv * 16 + rj) * S_UP + rq * 16];
        float4 b0 = *(const float4*)&base[0];
        float4 b1 = *(const float4*)&base[4];
        float4 b2 = *(const float4*)&base[8];
        float4 b3 = *(const float4*)&base[12];
        float s = b0.x + b0.y + b0.z + b0.w + b1.x + b1.y + b1.z + b1.w
                + b2.x + b2.y + b2.z + b2.w + b3.x + b3.y + b3.z + b3.w;
        s += __shfl_down(s, 1);
        s += __shfl_down(s, 2);
        if (rq == 0) At[rj][rwv] = s;
    }

    // ---- phase 3: O partials, wave w covers k in [50w, 50w+50) ----
    {
        float4 po[4];
#pragma unroll
        for (int f = 0; f < 4; ++f) po[f] = make_float4(0.f, 0.f, 0.f, 0.f);
#pragma unroll
        for (int kk = 0; kk < 4; ++kk) {
            float4 wv = *(const float4*)&W4[kb + kk][0];
            float4 fv = pf[kk];
            po[0].x += wv.x * fv.x; po[0].y += wv.x * fv.y; po[0].z += wv.x * fv.z; po[0].w += wv.x * fv.w;
            po[1].x += wv.y * fv.x; po[1].y += wv.y * fv.y; po[1].z += wv.y * fv.z; po[1].w += wv.y * fv.w;
            po[2].x += wv.z * fv.x; po[2].y += wv.z * fv.y; po[2].z += wv.z * fv.z; po[2].w += wv.z * fv.w;
            po[3].x += wv.w * fv.x; po[3].y += wv.w * fv.y; po[3].z += wv.w * fv.z; po[3].w += wv.w * fv.w;
        }
#pragma unroll 6
        for (int kk = 4; kk < 50; ++kk) {
            float4 wv = *(const float4*)&W4[kb + kk][0];
            float4 fv = fB4[(size_t)(kb + kk) * 64 + l];
            po[0].x += wv.x * fv.x; po[0].y += wv.x * fv.y; po[0].z += wv.x * fv.z; po[0].w += wv.x * fv.w;
            po[1].x += wv.y * fv.x; po[1].y += wv.y * fv.y; po[1].z += wv.y * fv.z; po[1].w += wv.y * fv.w;
            po[2].x += wv.z * fv.x; po[2].y += wv.z * fv.y; po[2].z += wv.z * fv.z; po[2].w += wv.z * fv.w;
            po[3].x += wv.w * fv.x; po[3].y += wv.w * fv.y; po[3].z += wv.w * fv.z; po[3].w += wv.w * fv.w;
        }
        // one ds_write_b128 per frame
#pragma unroll
        for (int f = 0; f < 4; ++f)
            *(float4*)&opool[((w * 4 + f) * 64 + l) * 4] = po[f];
    }
    __syncthreads();   // barrier 2: O-partials + At visible

    // ---- final: wave = frame, lane = 4 consecutive d (all-vector epilogue) ----
    {
        const int f = tid >> 6, d4 = (tid & 63) * 4;
        float4 v = make_float4(0.f, 0.f, 0.f, 0.f);
#pragma unroll
        for (int ww = 0; ww < 4; ++ww) {   // contiguous b128 reads, conflict-free
            float4 pv = *(const float4*)&opool[(ww * 4 + f) * 256 + d4];
            v.x += pv.x; v.y += pv.y; v.z += pv.z; v.w += pv.w;
        }
        float4 ab = *(const float4*)&p2_b[d4];
        v.x += ab.x; v.y += ab.y; v.z += ab.z; v.w += ab.w;
#pragma unroll
        for (int p = 0; p < 16; ++p) {
            float4 pw = *(const float4*)&p2_w[p * DIM_ + d4];
            float a = At[p][f];                 // wave-uniform broadcast
            v.x += a * pw.x; v.y += a * pw.y; v.z += a * pw.z; v.w += a * pw.w;
        }
        *(float4*)&out[((size_t)b * T_ + t0 + f) * DIM_ + d4] = v;
    }
}

// ---------------------------------------------------------------------------
extern "C" void kernel_launch(void* const* d_in, const int* in_sizes, int n_in,
                              void* d_out, int out_size, void* d_ws, size_t ws_size,
                              hipStream_t stream) {
    const float* durations = (const float*)d_in[1];
    const float* features  = (const float*)d_in[2];
    const float* conv1_w   = (const float*)d_in[3];
    const float* conv1_b   = (const float*)d_in[4];
    const float* conv2_w   = (const float*)d_in[5];
    const float* conv2_b   = (const float*)d_in[6];
    const float* sw1_w1    = (const float*)d_in[7];
    const float* sw1_b1    = (const float*)d_in[8];
    const float* sw1_w2    = (const float*)d_in[9];
    const float* sw1_b2    = (const float*)d_in[10];
    const float* sw2_w1    = (const float*)d_in[11];
    const float* sw2_b1    = (const float*)d_in[12];
    const float* sw2_w2    = (const float*)d_in[13];
    const float* sw2_b2    = (const float*)d_in[14];
    const float* p1_w      = (const float*)d_in[15];
    const float* p1_b      = (const float*)d_in[16];
    const float* p2_w      = (const float*)d_in[17];
    const float* p2_b      = (const float*)d_in[18];
    float* out = (float*)d_out;

    float* cw = (float*)d_ws;   // [B][K][20] token-major consts + [16][16] w2T tail

    prep_kernel<<<dim3(50, B_), 256, 0, stream>>>(
        durations, features, conv1_w, conv1_b, conv2_w, conv2_b,
        sw1_w1, sw1_b1, sw1_w2, sw2_w1, sw2_b1, cw);
    main_kernel<<<dim3(T_ / 4, B_), 256, 0, stream>>>(
        features, cw,
        sw1_w1, sw1_b2,
        sw2_w1, sw2_w2, sw2_b2,
        p1_w, p1_b, p2_w, p2_b, out);
}

// Round 5
// 119.771 us; speedup vs baseline: 1.0373x; 1.0373x over previous
//
#include <hip/hip_runtime.h>
#include <math.h>

#define B_   4
#define K_   200
#define DIM_ 256
#define T_   800

#define S_UP 68   // padded row stride for the A-partial transpose pool
#define CW_R 20   // padded const row: [beta0, beta1, B0..B15, pad, pad] (80 B)

__device__ __forceinline__ float silu_f(float x) {
    // x * rcp(1+e^-x): v_exp + v_add + v_rcp + v_mul (vs ~9-op IEEE divide seq)
    return x * __builtin_amdgcn_rcpf(1.0f + __expf(-x));
}

// ---------------------------------------------------------------------------
// Prep: conv (wave=token, lane=4-ch slice, coalesced) + scan + const folding.
// Writes cw[b][k][0..17]: 0 beta0, 1 beta1, 2..17 B_j  (token-major, 20-pad).
// Also writes w2T (sw1_w2 transposed) at cw + B*K*20 for scalar-load access
// in main. Grid (50, B_), 256 threads.
// ---------------------------------------------------------------------------
__global__ __launch_bounds__(256) void prep_kernel(
        const float* __restrict__ dur,
        const float* __restrict__ feats,
        const float* __restrict__ c1w, const float* __restrict__ c1b,
        const float* __restrict__ c2w, const float* __restrict__ c2b,
        const float* __restrict__ sw1_w1, const float* __restrict__ sw1_b1,
        const float* __restrict__ sw1_w2,
        const float* __restrict__ sw2_w1, const float* __restrict__ sw2_b1,
        float* __restrict__ cw) {
    const int b = blockIdx.y, k0 = blockIdx.x * 4;
    const int tid = threadIdx.x, w = tid >> 6, l = tid & 63;

    __shared__ float wT[16][772];        // wT[oc][tap*256+c]  (oc>=8 -> conv2)
    __shared__ float red[64][S_UP];      // cross-lane reduce scratch
    __shared__ float sSc[K_], sEc[K_];
    __shared__ float sfeat[4][16];       // conv outputs (post-silu)

    // block (0,0): transpose sw1_w2 into workspace tail (w2T[j][p] = w2[p][j])
    if (blockIdx.x == 0 && blockIdx.y == 0) {
        cw[(size_t)B_ * K_ * CW_R + tid] = sw1_w2[((tid & 15) * 16) + (tid >> 4)];
    }

    // stage transposed conv weights (reads coalesced)
    for (int i = tid; i < 3 * DIM_ * 8; i += 256) {
        int tc = i >> 3, o = i & 7;
        wT[o][tc]     = c1w[i];
        wT[8 + o][tc] = c2w[i];
    }
    // wave 0: inclusive scan of 200 durations
    if (tid < 64) {
        float4 dv = make_float4(0.f, 0.f, 0.f, 0.f);
        if (tid < 50) dv = *(const float4*)&dur[b * K_ + tid * 4];
        float s0 = dv.x, s1 = s0 + dv.y, s2 = s1 + dv.z, s3 = s2 + dv.w;
        float sc = s3;
#pragma unroll
        for (int off = 1; off < 64; off <<= 1) {
            float v = __shfl_up(sc, off);
            if (tid >= off) sc += v;
        }
        float excl = sc - s3;
        if (tid < 50) {
            *(float4*)&sSc[tid * 4] = make_float4(excl, excl + s0, excl + s1, excl + s2);
            *(float4*)&sEc[tid * 4] = make_float4(excl + s0, excl + s1, excl + s2, excl + s3);
        }
    }
    __syncthreads();

    // conv: wave w owns token k0+w; lane l owns channels 4l..4l+3
    {
        const int k = k0 + w;
        const float4* f4 = (const float4*)feats;
        float4 fv[3];
#pragma unroll
        for (int tap = 0; tap < 3; ++tap) {
            int kk = k - 1 + tap;
            bool valid = (kk >= 0 && kk < K_);
            int kc = valid ? kk : 0;
            float4 v = f4[(size_t)(b * K_ + kc) * 64 + l];
            fv[tap] = valid ? v : make_float4(0.f, 0.f, 0.f, 0.f);
        }
        float acc[16];
#pragma unroll
        for (int oc = 0; oc < 16; ++oc) acc[oc] = 0.f;
#pragma unroll
        for (int tap = 0; tap < 3; ++tap) {
#pragma unroll
            for (int oc = 0; oc < 16; ++oc) {
                float4 wv = *(const float4*)&wT[oc][tap * DIM_ + 4 * l];
                acc[oc] += fv[tap].x * wv.x + fv[tap].y * wv.y
                         + fv[tap].z * wv.z + fv[tap].w * wv.w;
            }
        }
#pragma unroll
        for (int oc = 0; oc < 16; ++oc) red[w * 16 + oc][l] = acc[oc];
    }
    __syncthreads();
    // reduce 64 lanes -> sfeat
    {
        const int rwv = tid >> 6, oc = (tid >> 2) & 15, rq = tid & 3;
        const float* base = &red[rwv * 16 + oc][rq * 16];
        float4 b0 = *(const float4*)&base[0];
        float4 b1 = *(const float4*)&base[4];
        float4 b2 = *(const float4*)&base[8];
        float4 b3 = *(const float4*)&base[12];
        float s = b0.x + b0.y + b0.z + b0.w + b1.x + b1.y + b1.z + b1.w
                + b2.x + b2.y + b2.z + b2.w + b3.x + b3.y + b3.z + b3.w;
        s += __shfl_down(s, 1);
        s += __shfl_down(s, 2);
        if (rq == 0) {
            float bias = (oc < 8) ? c1b[oc] : c2b[oc & 7];
            sfeat[rwv][oc] = silu_f(s + bias);
        }
    }
    __syncthreads();

    // consts for this block's 4 tokens (token-major rows)
    if (tid < 64) {                       // B_j: j = tid>>2, token = tid&3
        const int j = tid >> 2, klc = tid & 3, kk = k0 + klc;
        float st = sSc[kk], en = sEc[kk];
        float a = sw1_b1[j] - st * sw1_w1[j] + en * sw1_w1[16 + j];
#pragma unroll
        for (int i = 0; i < 8; ++i) a += sfeat[klc][i] * sw1_w1[(2 + i) * 16 + j];
        cw[(size_t)(b * K_ + kk) * CW_R + 2 + j] = a;
    } else if (tid < 72) {                // betas
        const int idx = tid - 64, which = idx >> 2, klc = idx & 3, kk = k0 + klc;
        float st = sSc[kk], en = sEc[kk];
        float a = sw2_b1[which] - st * sw2_w1[which] + en * sw2_w1[2 + which];
#pragma unroll
        for (int i = 0; i < 8; ++i) a += sfeat[klc][8 + i] * sw2_w1[(2 + i) * 2 + which];
        cw[(size_t)(b * K_ + kk) * CW_R + which] = a;
    }
}

// ---------------------------------------------------------------------------
// Main: 4 frames/block (wave w <-> frame t0+w), grid (T/4, B), 256 thr.
// launch_bounds(256,4): liveness reordered so peak ~110 VGPR (hmat computed
// at unpack time, Bv never materialized; pf issued after phase 2). 4 blocks/
// CU x 37.4KB LDS = 149.5KB <= 160KB -> all 800 blocks co-resident, no tail.
// Per-value arithmetic identical to the 119.9us R3 kernel.
// ---------------------------------------------------------------------------
__global__ __launch_bounds__(256, 4) void main_kernel(
        const float* __restrict__ feats,
        const float* __restrict__ cw,
        const float* __restrict__ sw1_w1, const float* __restrict__ sw1_b2,
        const float* __restrict__ sw2_w1, const float* __restrict__ sw2_w2,
        const float* __restrict__ sw2_b2,
        const float* __restrict__ p1_w,   const float* __restrict__ p1_b,
        const float* __restrict__ p2_w,   const float* __restrict__ p2_b,
        float* __restrict__ out) {
    const int t0 = blockIdx.x * 4, b = blockIdx.y;
    const int tid = threadIdx.x, w = tid >> 6, l = tid & 63;
    const int t = t0 + w;

    __shared__ alignas(16) float apool[64 * S_UP];   // A-partials (transpose pool)
    __shared__ alignas(16) float opool[16 * 256];    // O-partials [(w*4+f)][256]
    __shared__ alignas(16) float W4[K_][4];
    __shared__ alignas(16) float At[16][4];

    const float* __restrict__ w2T = cw + (size_t)B_ * K_ * CW_R;  // [j][p], uniform

    const float* cbg = cw + (size_t)b * K_ * CW_R;
    int kc[4];
#pragma unroll
    for (int i = 0; i < 4; ++i) { int k = l + 64 * i; kc[i] = (k < K_) ? k : (K_ - 1); }

    const float tf = (float)t;
    float ajt[16];
#pragma unroll
    for (int j = 0; j < 16; ++j) ajt[j] = (sw1_w1[j] - sw1_w1[16 + j]) * tf;

    // ---- const-row loads (5 float4 each) -> c0/c1 + hmat directly (Bv folded
    //      away at unpack; Bq registers die here, freeing 80 VGPRs) ----
    float c0[4], c1[4], hmat[4][16];
#pragma unroll
    for (int i = 0; i < 4; ++i) {
        const float* base = cbg + (size_t)kc[i] * CW_R;
        float r[20];
#pragma unroll
        for (int q = 0; q < 5; ++q) *(float4*)&r[4 * q] = *(const float4*)(base + 4 * q);
        c0[i] = r[0]; c1[i] = r[1];
#pragma unroll
        for (int j = 0; j < 16; ++j) hmat[i][j] = silu_f(ajt[j] + r[2 + j]);
    }

    const float a0 = sw2_w1[0] - sw2_w1[2], a1 = sw2_w1[1] - sw2_w1[3];
    const float rw20 = sw2_w2[0], rw21 = sw2_w2[1], rw22 = sw2_w2[2], rw23 = sw2_w2[3];
    const float rb20 = sw2_b2[0], rb21 = sw2_b2[1];
    const float p10 = p1_w[0], p11 = p1_w[1], p1b0 = p1_b[0];

    // ---- phase 1: logits + wave softmax ----
    float lg[4];
#pragma unroll
    for (int i = 0; i < 4; ++i) {
        float h0 = silu_f(fmaf(a0, tf, c0[i]));
        float h1 = silu_f(fmaf(a1, tf, c1[i]));
        float g0 = silu_f(rb20 + h0 * rw20 + h1 * rw22);
        float g1 = silu_f(rb21 + h0 * rw21 + h1 * rw23);
        lg[i] = (l + 64 * i < K_) ? (g0 * p10 + g1 * p11 + p1b0) : -1e30f;
    }
    float m = fmaxf(fmaxf(lg[0], lg[1]), fmaxf(lg[2], lg[3]));
#pragma unroll
    for (int off = 32; off > 0; off >>= 1) m = fmaxf(m, __shfl_xor(m, off));
    float e0 = __expf(lg[0] - m), e1 = __expf(lg[1] - m);
    float e2 = __expf(lg[2] - m), e3 = __expf(lg[3] - m);
    float ssum = e0 + e1 + e2 + e3;
#pragma unroll
    for (int off = 32; off > 0; off >>= 1) ssum += __shfl_xor(ssum, off);
    float inv = __builtin_amdgcn_rcpf(ssum);
    float wgt[4] = { e0 * inv, e1 * inv, e2 * inv, e3 * inv };
#pragma unroll
    for (int i = 0; i < 4; ++i) { int k = l + 64 * i; if (k < K_) W4[k][w] = wgt[i]; }

    // ---- phase 2: acc[j] = sum_i wgt_i * silu(hmat_i @ w2[:,j] + b2_j) ----
    float acc[16];
#pragma unroll
    for (int j = 0; j < 16; ++j) {
        const float* __restrict__ wj = w2T + j * 16;   // uniform -> s_load
        const float bj = sw1_b2[j];
        float s = 0.f;
#pragma unroll
        for (int i = 0; i < 4; ++i) {
            float c = bj;
#pragma unroll
            for (int p = 0; p < 16; ++p) c += hmat[i][p] * wj[p];
            s += wgt[i] * silu_f(c);
        }
        acc[j] = s;
    }
#pragma unroll
    for (int j = 0; j < 16; ++j) apool[(w * 16 + j) * S_UP + l] = acc[j];

    // ---- issue phase-3 prefetch now: latency overlaps barrier-1 wait ----
    const int kb = w * 50;
    const float4* fB4 = (const float4*)(feats + (size_t)b * K_ * DIM_);
    float4 pf[8];
#pragma unroll
    for (int q = 0; q < 8; ++q) pf[q] = fB4[(size_t)(kb + q) * 64 + l];

    __syncthreads();   // barrier 1: A-partials + W4 visible

    // ---- A transpose-reduce (reads apool; phase 3 writes opool — disjoint) ----
    {
        const int rwv = tid >> 6, rj = (tid >> 2) & 15, rq = tid & 3;
        const float* base = &apool[(rwv * 16 + rj) * S_UP + rq * 16];
        float4 b0 = *(const float4*)&base[0];
        float4 b1 = *(const float4*)&base[4];
        float4 b2 = *(const float4*)&base[8];
        float4 b3 = *(const float4*)&base[12];
        float s = b0.x + b0.y + b0.z + b0.w + b1.x + b1.y + b1.z + b1.w
                + b2.x + b2.y + b2.z + b2.w + b3.x + b3.y + b3.z + b3.w;
        s += __shfl_down(s, 1);
        s += __shfl_down(s, 2);
        if (rq == 0) At[rj][rwv] = s;
    }

    // ---- phase 3: O partials, wave w covers k in [50w, 50w+50) ----
    {
        float4 po[4];
#pragma unroll
        for (int f = 0; f < 4; ++f) po[f] = make_float4(0.f, 0.f, 0.f, 0.f);
#pragma unroll
        for (int kk = 0; kk < 8; ++kk) {
            float4 wv = *(const float4*)&W4[kb + kk][0];
            float4 fv = pf[kk];
            po[0].x += wv.x * fv.x; po[0].y += wv.x * fv.y; po[0].z += wv.x * fv.z; po[0].w += wv.x * fv.w;
            po[1].x += wv.y * fv.x; po[1].y += wv.y * fv.y; po[1].z += wv.y * fv.z; po[1].w += wv.y * fv.w;
            po[2].x += wv.z * fv.x; po[2].y += wv.z * fv.y; po[2].z += wv.z * fv.z; po[2].w += wv.z * fv.w;
            po[3].x += wv.w * fv.x; po[3].y += wv.w * fv.y; po[3].z += wv.w * fv.z; po[3].w += wv.w * fv.w;
        }
#pragma unroll 6
        for (int kk = 8; kk < 50; ++kk) {
            float4 wv = *(const float4*)&W4[kb + kk][0];
            float4 fv = fB4[(size_t)(kb + kk) * 64 + l];
            po[0].x += wv.x * fv.x; po[0].y += wv.x * fv.y; po[0].z += wv.x * fv.z; po[0].w += wv.x * fv.w;
            po[1].x += wv.y * fv.x; po[1].y += wv.y * fv.y; po[1].z += wv.y * fv.z; po[1].w += wv.y * fv.w;
            po[2].x += wv.z * fv.x; po[2].y += wv.z * fv.y; po[2].z += wv.z * fv.z; po[2].w += wv.z * fv.w;
            po[3].x += wv.w * fv.x; po[3].y += wv.w * fv.y; po[3].z += wv.w * fv.z; po[3].w += wv.w * fv.w;
        }
        // one ds_write_b128 per frame
#pragma unroll
        for (int f = 0; f < 4; ++f)
            *(float4*)&opool[((w * 4 + f) * 64 + l) * 4] = po[f];
    }
    __syncthreads();   // barrier 2: O-partials + At visible

    // ---- final: wave = frame, lane = 4 consecutive d (all-vector epilogue) ----
    {
        const int f = tid >> 6, d4 = (tid & 63) * 4;
        float4 v = make_float4(0.f, 0.f, 0.f, 0.f);
#pragma unroll
        for (int ww = 0; ww < 4; ++ww) {   // contiguous b128 reads, conflict-free
            float4 pv = *(const float4*)&opool[(ww * 4 + f) * 256 + d4];
            v.x += pv.x; v.y += pv.y; v.z += pv.z; v.w += pv.w;
        }
        float4 ab = *(const float4*)&p2_b[d4];
        v.x += ab.x; v.y += ab.y; v.z += ab.z; v.w += ab.w;
#pragma unroll
        for (int p = 0; p < 16; ++p) {
            float4 pw = *(const float4*)&p2_w[p * DIM_ + d4];
            float a = At[p][f];                 // wave-uniform broadcast
            v.x += a * pw.x; v.y += a * pw.y; v.z += a * pw.z; v.w += a * pw.w;
        }
        *(float4*)&out[((size_t)b * T_ + t0 + f) * DIM_ + d4] = v;
    }
}

// ---------------------------------------------------------------------------
extern "C" void kernel_launch(void* const* d_in, const int* in_sizes, int n_in,
                              void* d_out, int out_size, void* d_ws, size_t ws_size,
                              hipStream_t stream) {
    const float* durations = (const float*)d_in[1];
    const float* features  = (const float*)d_in[2];
    const float* conv1_w   = (const float*)d_in[3];
    const float* conv1_b   = (const float*)d_in[4];
    const float* conv2_w   = (const float*)d_in[5];
    const float* conv2_b   = (const float*)d_in[6];
    const float* sw1_w1    = (const float*)d_in[7];
    const float* sw1_b1    = (const float*)d_in[8];
    const float* sw1_w2    = (const float*)d_in[9];
    const float* sw1_b2    = (const float*)d_in[10];
    const float* sw2_w1    = (const float*)d_in[11];
    const float* sw2_b1    = (const float*)d_in[12];
    const float* sw2_w2    = (const float*)d_in[13];
    const float* sw2_b2    = (const float*)d_in[14];
    const float* p1_w      = (const float*)d_in[15];
    const float* p1_b      = (const float*)d_in[16];
    const float* p2_w      = (const float*)d_in[17];
    const float* p2_b      = (const float*)d_in[18];
    float* out = (float*)d_out;

    float* cw = (float*)d_ws;   // [B][K][20] token-major consts + [16][16] w2T tail

    prep_kernel<<<dim3(50, B_), 256, 0, stream>>>(
        durations, features, conv1_w, conv1_b, conv2_w, conv2_b,
        sw1_w1, sw1_b1, sw1_w2, sw2_w1, sw2_b1, cw);
    main_kernel<<<dim3(T_ / 4, B_), 256, 0, stream>>>(
        features, cw,
        sw1_w1, sw1_b2,
        sw2_w1, sw2_w2, sw2_b2,
        p1_w, p1_b, p2_w, p2_b, out);
}